// Round 6
// baseline (808.063 us; speedup 1.0000x reference)
//
#include <hip/hip_runtime.h>

// ---------------------------------------------------------------------------
// Sparse voxel encoder, fp32 dense pipeline.
// d_out = [out2 (24^3*64) | out1 (24^3*64) | out0 (48^3*32)]
// (Round-1 source, resubmitted: R1-R4 benches all failed infra-side,
// so this version has never been measured.)
// ---------------------------------------------------------------------------

constexpr int D0 = 96;

// ---------------- scatter: coords/feats -> dense grid + occupancy ----------
__global__ void scatter_kernel(const int* __restrict__ coords,
                               const float* __restrict__ feats,
                               float* __restrict__ x, float* __restrict__ occ,
                               int N) {
    int n = blockIdx.x * blockDim.x + threadIdx.x;
    if (n >= N) return;
    int i = coords[n * 3 + 0], j = coords[n * 3 + 1], k = coords[n * 3 + 2];
    int flat = (i * D0 + j) * D0 + k;
    const float4* f4 = reinterpret_cast<const float4*>(feats + (size_t)n * 8);
    float4 a = f4[0], b = f4[1];
    float* dst = x + (size_t)flat * 8;
    atomicAdd(dst + 0, a.x); atomicAdd(dst + 1, a.y);
    atomicAdd(dst + 2, a.z); atomicAdd(dst + 3, a.w);
    atomicAdd(dst + 4, b.x); atomicAdd(dst + 5, b.y);
    atomicAdd(dst + 6, b.z); atomicAdd(dst + 7, b.w);
    occ[flat] = 1.0f;
}

// ---------------- 2x2x2 max pool on occupancy ------------------------------
template <int GDO>
__global__ void pool_kernel(const float* __restrict__ occ_in,
                            float* __restrict__ occ_out) {
    int idx = blockIdx.x * blockDim.x + threadIdx.x;
    if (idx >= GDO * GDO * GDO) return;
    int x = idx % GDO, y = (idx / GDO) % GDO, z = idx / (GDO * GDO);
    constexpr int GDI = GDO * 2;
    float m = 0.f;
    #pragma unroll
    for (int dz = 0; dz < 2; dz++)
        #pragma unroll
        for (int dy = 0; dy < 2; dy++)
            #pragma unroll
            for (int dx = 0; dx < 2; dx++)
                m = fmaxf(m, occ_in[((z * 2 + dz) * GDI + y * 2 + dy) * GDI + x * 2 + dx]);
    occ_out[idx] = m;
}

// ---------------- 3x3x3 SAME conv, relu, occupancy mask --------------------
// Block: 256 threads. Each thread: 1 output voxel, CO_PER couts.
// LDS halo tile as float4[CC/4][NVp] with c4-stride padded so that the
// c4-fast staging writes hit distinct bank groups (pad = 8/(CC/4)).
// Reads: TX=8 tiles -> 8 consecutive lanes read 8 consecutive float4s
// (conflict-free). TX=4 tiles use REMAP lane mapping (tx,tzl in low bits;
// halo z-stride 36 == 4 mod 8) for the same effect.
// Weights are wave-uniform -> scalar (s_load) path.
template <int CIN, int COUT, int GD, int TX, int TY, int TZ, int CC, int COSPLIT,
          bool REMAP>
__global__ __launch_bounds__(256) void conv3_kernel(
    const float* __restrict__ in, const float* __restrict__ W,
    const float* __restrict__ bias, const float* __restrict__ occ,
    float* __restrict__ out) {
    constexpr int HX = TX + 2, HY = TY + 2, HZ = TZ + 2;
    constexpr int NV = HX * HY * HZ;
    constexpr int Q = CC / 4;            // float4s per voxel per chunk
    constexpr int PADV = 8 / Q;          // bank-group pad for c4 stride
    constexpr int NVp = NV + PADV;
    constexpr int VOX = TX * TY * TZ;
    constexpr int NG = 256 / VOX;
    constexpr int CO_PER = COUT / COSPLIT / NG;
    constexpr int NCH = CIN / CC;
    __shared__ float4 lds4[Q * NVp];

    const int t = threadIdx.x;
    constexpr int NBX = GD / TX;
    const int cs = blockIdx.x / NBX;
    const int bx = blockIdx.x % NBX;
    const int x0 = bx * TX, y0 = blockIdx.y * TY, z0 = blockIdx.z * TZ;
    const int v = t & (VOX - 1);
    const int g = t / VOX;  // wave-uniform (VOX >= 64)
    int tx, ty, tz;
    if (REMAP) {  // VOX==64, 4x4x4: lanes 0-7 span (tx, tz&1)
        tx = v & 3;
        ty = (v >> 3) & 3;
        tz = ((v >> 2) & 1) | (((v >> 5) & 1) << 1);
    } else {
        tx = v % TX;
        ty = (v / TX) % TY;
        tz = v / (TX * TY);
    }
    const int co_base = __builtin_amdgcn_readfirstlane((cs * NG + g) * CO_PER);

    float acc[CO_PER];
    #pragma unroll
    for (int i = 0; i < CO_PER; i++) acc[i] = 0.f;

    for (int ch = 0; ch < NCH; ++ch) {
        // ---- stage halo tile (c4-fast: coalesced global, padded LDS) ----
        constexpr int T4 = NV * Q;
        for (int idx = t; idx < T4; idx += 256) {
            int c4 = idx & (Q - 1);
            int vox = idx / Q;
            int hx = vox % HX, hy = (vox / HX) % HY, hz = vox / (HX * HY);
            int gx = x0 + hx - 1, gy = y0 + hy - 1, gz = z0 + hz - 1;
            float4 val = make_float4(0.f, 0.f, 0.f, 0.f);
            if (gx >= 0 && gx < GD && gy >= 0 && gy < GD && gz >= 0 && gz < GD) {
                val = *reinterpret_cast<const float4*>(
                    in + (size_t)((gz * GD + gy) * GD + gx) * CIN + ch * CC + c4 * 4);
            }
            lds4[c4 * NVp + vox] = val;
        }
        __syncthreads();
        // ---- compute ----
        #pragma unroll 1
        for (int kz = 0; kz < 3; ++kz) {
            #pragma unroll 1
            for (int ky = 0; ky < 3; ++ky) {
                const int vrow = (tz + kz) * (HX * HY) + (ty + ky) * HX + tx;
                #pragma unroll
                for (int kx = 0; kx < 3; ++kx) {
                    const int tap = (kz * 3 + ky) * 3 + kx;
                    const int vin = vrow + kx;
                    #pragma unroll
                    for (int c4 = 0; c4 < Q; ++c4) {
                        float4 iv = lds4[c4 * NVp + vin];
                        const float* wp =
                            W + (size_t)(tap * CIN + ch * CC + c4 * 4) * COUT + co_base;
                        #pragma unroll
                        for (int o4 = 0; o4 < CO_PER / 4; ++o4) {
                            float4 w0 = *reinterpret_cast<const float4*>(wp + 0 * COUT + o4 * 4);
                            float4 w1 = *reinterpret_cast<const float4*>(wp + 1 * COUT + o4 * 4);
                            float4 w2 = *reinterpret_cast<const float4*>(wp + 2 * COUT + o4 * 4);
                            float4 w3 = *reinterpret_cast<const float4*>(wp + 3 * COUT + o4 * 4);
                            acc[o4 * 4 + 0] += iv.x * w0.x + iv.y * w1.x + iv.z * w2.x + iv.w * w3.x;
                            acc[o4 * 4 + 1] += iv.x * w0.y + iv.y * w1.y + iv.z * w2.y + iv.w * w3.y;
                            acc[o4 * 4 + 2] += iv.x * w0.z + iv.y * w1.z + iv.z * w2.z + iv.w * w3.z;
                            acc[o4 * 4 + 3] += iv.x * w0.w + iv.y * w1.w + iv.z * w2.w + iv.w * w3.w;
                        }
                    }
                }
            }
        }
        if (ch + 1 < NCH) __syncthreads();
    }
    // ---- epilogue: bias, relu, occupancy mask ----
    int oz = z0 + tz, oy = y0 + ty, ox = x0 + tx;
    int oflat = (oz * GD + oy) * GD + ox;
    float o = occ[oflat];
    float* op = out + (size_t)oflat * COUT + co_base;
    #pragma unroll
    for (int o4 = 0; o4 < CO_PER / 4; o4++) {
        float4 r;
        r.x = fmaxf(acc[o4 * 4 + 0] + bias[co_base + o4 * 4 + 0], 0.f) * o;
        r.y = fmaxf(acc[o4 * 4 + 1] + bias[co_base + o4 * 4 + 1], 0.f) * o;
        r.z = fmaxf(acc[o4 * 4 + 2] + bias[co_base + o4 * 4 + 2], 0.f) * o;
        r.w = fmaxf(acc[o4 * 4 + 3] + bias[co_base + o4 * 4 + 3], 0.f) * o;
        *reinterpret_cast<float4*>(op + o4 * 4) = r;
    }
}

// ---------------- 2x2x2 stride-2 VALID conv, relu, occupancy mask ----------
// Block: 256 threads = 64 output voxels (4x4x4) x 4 cout groups.
template <int CIN, int COUT, int GDI, int CC>
__global__ __launch_bounds__(256) void convd_kernel(
    const float* __restrict__ in, const float* __restrict__ W,
    const float* __restrict__ bias, const float* __restrict__ occ,
    float* __restrict__ out) {
    constexpr int GDO = GDI / 2;
    constexpr int VOX = 64, NG = 4;
    constexpr int CO_PER = COUT / NG;
    constexpr int HX = 8, HY = 8, HZ = 8, NV = HX * HY * HZ;
    constexpr int Q = CC / 4;
    constexpr int NVp = NV + 8 / Q;  // staging write-conflict pad
    constexpr int NCH = CIN / CC;
    __shared__ float4 lds4[Q * NVp];

    const int t = threadIdx.x;
    const int x0 = blockIdx.x * 4, y0 = blockIdx.y * 4, z0 = blockIdx.z * 4;
    const int v = t & 63;
    const int g = t >> 6;
    const int tx = v % 4, ty = (v / 4) % 4, tz = v / 16;
    const int co_base = __builtin_amdgcn_readfirstlane(g * CO_PER);

    float acc[CO_PER];
    #pragma unroll
    for (int i = 0; i < CO_PER; i++) acc[i] = 0.f;

    for (int ch = 0; ch < NCH; ++ch) {
        constexpr int T4 = NV * Q;
        for (int idx = t; idx < T4; idx += 256) {
            int c4 = idx & (Q - 1);
            int vox = idx / Q;
            int hx = vox % HX, hy = (vox / HX) % HY, hz = vox / (HX * HY);
            int gx = x0 * 2 + hx, gy = y0 * 2 + hy, gz = z0 * 2 + hz;
            lds4[c4 * NVp + vox] = *reinterpret_cast<const float4*>(
                in + (size_t)((gz * GDI + gy) * GDI + gx) * CIN + ch * CC + c4 * 4);
        }
        __syncthreads();
        #pragma unroll 1
        for (int kz = 0; kz < 2; ++kz) {
            #pragma unroll
            for (int ky = 0; ky < 2; ++ky) {
                #pragma unroll
                for (int kx = 0; kx < 2; ++kx) {
                    const int tap = kz * 4 + ky * 2 + kx;
                    const int vin = (tz * 2 + kz) * (HX * HY) + (ty * 2 + ky) * HX + (tx * 2 + kx);
                    #pragma unroll
                    for (int c4 = 0; c4 < Q; ++c4) {
                        float4 iv = lds4[c4 * NVp + vin];
                        const float* wp =
                            W + (size_t)(tap * CIN + ch * CC + c4 * 4) * COUT + co_base;
                        #pragma unroll
                        for (int o4 = 0; o4 < CO_PER / 4; ++o4) {
                            float4 w0 = *reinterpret_cast<const float4*>(wp + 0 * COUT + o4 * 4);
                            float4 w1 = *reinterpret_cast<const float4*>(wp + 1 * COUT + o4 * 4);
                            float4 w2 = *reinterpret_cast<const float4*>(wp + 2 * COUT + o4 * 4);
                            float4 w3 = *reinterpret_cast<const float4*>(wp + 3 * COUT + o4 * 4);
                            acc[o4 * 4 + 0] += iv.x * w0.x + iv.y * w1.x + iv.z * w2.x + iv.w * w3.x;
                            acc[o4 * 4 + 1] += iv.x * w0.y + iv.y * w1.y + iv.z * w2.y + iv.w * w3.y;
                            acc[o4 * 4 + 2] += iv.x * w0.z + iv.y * w1.z + iv.z * w2.z + iv.w * w3.z;
                            acc[o4 * 4 + 3] += iv.x * w0.w + iv.y * w1.w + iv.z * w2.w + iv.w * w3.w;
                        }
                    }
                }
            }
        }
        if (ch + 1 < NCH) __syncthreads();
    }
    int oz = z0 + tz, oy = y0 + ty, ox = x0 + tx;
    int oflat = (oz * GDO + oy) * GDO + ox;
    float o = occ[oflat];
    float* op = out + (size_t)oflat * COUT + co_base;
    #pragma unroll
    for (int o4 = 0; o4 < CO_PER / 4; o4++) {
        float4 r;
        r.x = fmaxf(acc[o4 * 4 + 0] + bias[co_base + o4 * 4 + 0], 0.f) * o;
        r.y = fmaxf(acc[o4 * 4 + 1] + bias[co_base + o4 * 4 + 1], 0.f) * o;
        r.z = fmaxf(acc[o4 * 4 + 2] + bias[co_base + o4 * 4 + 2], 0.f) * o;
        r.w = fmaxf(acc[o4 * 4 + 3] + bias[co_base + o4 * 4 + 3], 0.f) * o;
        *reinterpret_cast<float4*>(op + o4 * 4) = r;
    }
}

// ---------------------------------------------------------------------------
extern "C" void kernel_launch(void* const* d_in, const int* in_sizes, int n_in,
                              void* d_out, int out_size, void* d_ws, size_t ws_size,
                              hipStream_t stream) {
    const int* coords = (const int*)d_in[0];
    const float* feats = (const float*)d_in[1];
    const float* W0 = (const float*)d_in[2];
    const float* b0 = (const float*)d_in[3];
    const float* Wd0 = (const float*)d_in[4];
    const float* bd0 = (const float*)d_in[5];
    const float* W1 = (const float*)d_in[6];
    const float* b1 = (const float*)d_in[7];
    const float* Wd1 = (const float*)d_in[8];
    const float* bd1 = (const float*)d_in[9];
    const float* W2 = (const float*)d_in[10];
    const float* b2 = (const float*)d_in[11];
    const int N = in_sizes[0] / 3;

    // workspace layout (floats)
    float* ws = (float*)d_ws;
    float* x = ws;
    float* h1 = ws;  // reuse x region after conv0 consumes it
    float* occ = ws + 7077888;
    float* h = ws + 7962624;
    float* occ0 = ws + 22118400;
    float* occ1 = ws + 22228992;

    float* out = (float*)d_out;
    float* out2 = out;            // 24^3*64
    float* out1 = out + 884736;   // 24^3*64
    float* out0 = out + 1769472;  // 48^3*32

    hipMemsetAsync(x, 0, (size_t)(7077888 + 884736) * sizeof(float), stream);

    scatter_kernel<<<(N + 255) / 256, 256, 0, stream>>>(coords, feats, x, occ, N);
    pool_kernel<48><<<(110592 + 255) / 256, 256, 0, stream>>>(occ, occ0);
    pool_kernel<24><<<(13824 + 255) / 256, 256, 0, stream>>>(occ0, occ1);

    // conv0: 96^3, 8->16, tile 8x8x4 (256 vox, CO_PER=16)
    conv3_kernel<8, 16, 96, 8, 8, 4, 8, 1, false>
        <<<dim3(12, 12, 24), 256, 0, stream>>>(x, W0, b0, occ, h);
    // convd0: 96->48, 16->32
    convd_kernel<16, 32, 96, 16>
        <<<dim3(12, 12, 12), 256, 0, stream>>>(h, Wd0, bd0, occ0, out0);
    // conv1: 48^3, 32->32, tile 8x4x4 (128 vox x 2 groups, CO_PER=16, CC=32)
    conv3_kernel<32, 32, 48, 8, 4, 4, 32, 1, false>
        <<<dim3(6, 12, 12), 256, 0, stream>>>(out0, W1, b1, occ0, h1);
    // convd1: 48->24, 32->64
    convd_kernel<32, 64, 48, 16>
        <<<dim3(6, 6, 6), 256, 0, stream>>>(h1, Wd1, bd1, occ1, out1);
    // conv2: 24^3, 64->64, tile 4x4x4 REMAP, CO_PER=8, COSPLIT=2, CC=32
    conv3_kernel<64, 64, 24, 4, 4, 4, 32, 2, true>
        <<<dim3(12, 6, 6), 256, 0, stream>>>(out1, W2, b2, occ1, out2);
}

// Round 7
// 521.179 us; speedup vs baseline: 1.5505x; 1.5505x over previous
//
#include <hip/hip_runtime.h>

// ---------------------------------------------------------------------------
// Sparse voxel encoder, fp32 dense pipeline.
// d_out = [out2 (24^3*64) | out1 (24^3*64) | out0 (48^3*32)]
// R6: weights repacked per-launch into [tap][c4][o4][4ci*4co] contiguous
// blocks (scalar-load friendly), pure-fmaf accumulation, conv0 tap loops
// back to unroll-1 (SGPR pressure cliff with CO_PER=16 + kx-unroll).
// ---------------------------------------------------------------------------

constexpr int D0 = 96;

// ---------------- scatter: coords/feats -> dense grid + occupancy ----------
__global__ void scatter_kernel(const int* __restrict__ coords,
                               const float* __restrict__ feats,
                               float* __restrict__ x, float* __restrict__ occ,
                               int N) {
    int n = blockIdx.x * blockDim.x + threadIdx.x;
    if (n >= N) return;
    int i = coords[n * 3 + 0], j = coords[n * 3 + 1], k = coords[n * 3 + 2];
    int flat = (i * D0 + j) * D0 + k;
    const float4* f4 = reinterpret_cast<const float4*>(feats + (size_t)n * 8);
    float4 a = f4[0], b = f4[1];
    float* dst = x + (size_t)flat * 8;
    atomicAdd(dst + 0, a.x); atomicAdd(dst + 1, a.y);
    atomicAdd(dst + 2, a.z); atomicAdd(dst + 3, a.w);
    atomicAdd(dst + 4, b.x); atomicAdd(dst + 5, b.y);
    atomicAdd(dst + 6, b.z); atomicAdd(dst + 7, b.w);
    occ[flat] = 1.0f;
}

// ---------------- 2x2x2 max pool on occupancy ------------------------------
template <int GDO>
__global__ void pool_kernel(const float* __restrict__ occ_in,
                            float* __restrict__ occ_out) {
    int idx = blockIdx.x * blockDim.x + threadIdx.x;
    if (idx >= GDO * GDO * GDO) return;
    int x = idx % GDO, y = (idx / GDO) % GDO, z = idx / (GDO * GDO);
    constexpr int GDI = GDO * 2;
    float m = 0.f;
    #pragma unroll
    for (int dz = 0; dz < 2; dz++)
        #pragma unroll
        for (int dy = 0; dy < 2; dy++)
            #pragma unroll
            for (int dx = 0; dx < 2; dx++)
                m = fmaxf(m, occ_in[((z * 2 + dz) * GDI + y * 2 + dy) * GDI + x * 2 + dx]);
    occ_out[idx] = m;
}

// ---------------- weight repack -------------------------------------------
// dst[i]: i = (((tap*CIN4 + c4)*COUT4 + o4)*4 + r)*4 + c
//   == W[(tap*CIN + c4*4+r)*COUT + o4*4+c]
// Each (tap,c4,o4) block = 16 contiguous floats {ci0:4co, ci1:4co, ci2:4co, ci3:4co}.
__device__ inline void repack_one(const float* __restrict__ W,
                                  float* __restrict__ WR, int i, int CIN, int COUT) {
    int c = i & 3;
    int r = (i >> 2) & 3;
    int blk = i >> 4;
    int COUT4 = COUT >> 2, CIN4 = CIN >> 2;
    int o4 = blk % COUT4;          // pow2 -> shifts
    int c4 = (blk / COUT4) % CIN4;
    int tap = blk / (COUT4 * CIN4);
    WR[i] = W[((size_t)tap * CIN + c4 * 4 + r) * COUT + o4 * 4 + c];
}

// segment offsets (floats) inside WR region
constexpr int WR_W0 = 0;              // 27*8*16    = 3456
constexpr int WR_WD0 = 3456;          // 8*16*32    = 4096
constexpr int WR_W1 = 7552;           // 27*32*32   = 27648
constexpr int WR_WD1 = 35200;         // 8*32*64    = 16384
constexpr int WR_W2 = 51584;          // 27*64*64   = 110592
constexpr int WR_TOT = 162176;

__global__ void repack_all_kernel(const float* __restrict__ W0,
                                  const float* __restrict__ Wd0,
                                  const float* __restrict__ W1,
                                  const float* __restrict__ Wd1,
                                  const float* __restrict__ W2,
                                  float* __restrict__ WR) {
    int i = blockIdx.x * 256 + threadIdx.x;
    if (i < WR_WD0)          repack_one(W0,  WR + WR_W0,  i - WR_W0,  8, 16);
    else if (i < WR_W1)      repack_one(Wd0, WR + WR_WD0, i - WR_WD0, 16, 32);
    else if (i < WR_WD1)     repack_one(W1,  WR + WR_W1,  i - WR_W1,  32, 32);
    else if (i < WR_W2)      repack_one(Wd1, WR + WR_WD1, i - WR_WD1, 32, 64);
    else if (i < WR_TOT)     repack_one(W2,  WR + WR_W2,  i - WR_W2,  64, 64);
}

#define FMA4(av, rv, accv)                 \
    accv.x = fmaf(av, rv.x, accv.x);       \
    accv.y = fmaf(av, rv.y, accv.y);       \
    accv.z = fmaf(av, rv.z, accv.z);       \
    accv.w = fmaf(av, rv.w, accv.w);

// ---------------- 3x3x3 SAME conv, relu, occupancy mask --------------------
// Weights from repacked WR segment. KXU: unroll kx (scheduler window) or not
// (minimal SGPR pressure — conv0's CO_PER=16 x 3-tap hoist blew the budget).
template <int CIN, int COUT, int GD, int TX, int TY, int TZ, int CC, int COSPLIT,
          bool REMAP, bool KXU>
__global__ __launch_bounds__(256) void conv3_kernel(
    const float* __restrict__ in, const float* __restrict__ WR,
    const float* __restrict__ bias, const float* __restrict__ occ,
    float* __restrict__ out) {
    constexpr int HX = TX + 2, HY = TY + 2, HZ = TZ + 2;
    constexpr int NV = HX * HY * HZ;
    constexpr int Q = CC / 4;
    constexpr int PADV = 8 / Q;
    constexpr int NVp = NV + PADV;
    constexpr int VOX = TX * TY * TZ;
    constexpr int NG = 256 / VOX;
    constexpr int CO_PER = COUT / COSPLIT / NG;
    constexpr int NCH = CIN / CC;
    constexpr int CIN4 = CIN / 4, COUT4 = COUT / 4;
    __shared__ float4 lds4[Q * NVp];

    const int t = threadIdx.x;
    constexpr int NBX = GD / TX;
    const int cs = blockIdx.x / NBX;
    const int bx = blockIdx.x % NBX;
    const int x0 = bx * TX, y0 = blockIdx.y * TY, z0 = blockIdx.z * TZ;
    const int v = t & (VOX - 1);
    const int g = t / VOX;  // wave-uniform (VOX >= 64)
    int tx, ty, tz;
    if (REMAP) {  // VOX==64, 4x4x4
        tx = v & 3;
        ty = (v >> 3) & 3;
        tz = ((v >> 2) & 1) | (((v >> 5) & 1) << 1);
    } else {
        tx = v % TX;
        ty = (v / TX) % TY;
        tz = v / (TX * TY);
    }
    const int co_base = __builtin_amdgcn_readfirstlane((cs * NG + g) * CO_PER);
    const int co4b = co_base >> 2;
    const float4* wr4 = reinterpret_cast<const float4*>(WR);

    float4 acc4[CO_PER / 4];
    #pragma unroll
    for (int i = 0; i < CO_PER / 4; i++) acc4[i] = make_float4(0.f, 0.f, 0.f, 0.f);

    for (int ch = 0; ch < NCH; ++ch) {
        // ---- stage halo tile ----
        constexpr int T4 = NV * Q;
        for (int idx = t; idx < T4; idx += 256) {
            int c4 = idx & (Q - 1);
            int vox = idx / Q;
            int hx = vox % HX, hy = (vox / HX) % HY, hz = vox / (HX * HY);
            int gx = x0 + hx - 1, gy = y0 + hy - 1, gz = z0 + hz - 1;
            float4 val = make_float4(0.f, 0.f, 0.f, 0.f);
            if (gx >= 0 && gx < GD && gy >= 0 && gy < GD && gz >= 0 && gz < GD) {
                val = *reinterpret_cast<const float4*>(
                    in + (size_t)((gz * GD + gy) * GD + gx) * CIN + ch * CC + c4 * 4);
            }
            lds4[c4 * NVp + vox] = val;
        }
        __syncthreads();

        auto body = [&](int tap, int vin) {
            #pragma unroll
            for (int c4 = 0; c4 < Q; ++c4) {
                float4 iv = lds4[c4 * NVp + vin];
                const float4* wp =
                    wr4 + ((size_t)(tap * CIN4 + ch * Q + c4) * COUT4) * 4;
                #pragma unroll
                for (int o4 = 0; o4 < CO_PER / 4; ++o4) {
                    const float4* w4 = wp + (co4b + o4) * 4;
                    float4 r0 = w4[0], r1 = w4[1], r2 = w4[2], r3 = w4[3];
                    FMA4(iv.x, r0, acc4[o4]);
                    FMA4(iv.y, r1, acc4[o4]);
                    FMA4(iv.z, r2, acc4[o4]);
                    FMA4(iv.w, r3, acc4[o4]);
                }
            }
        };

        if constexpr (KXU) {
            #pragma unroll 1
            for (int kz = 0; kz < 3; ++kz) {
                #pragma unroll 1
                for (int ky = 0; ky < 3; ++ky) {
                    const int vrow = (tz + kz) * (HX * HY) + (ty + ky) * HX + tx;
                    #pragma unroll
                    for (int kx = 0; kx < 3; ++kx)
                        body((kz * 3 + ky) * 3 + kx, vrow + kx);
                }
            }
        } else {
            #pragma unroll 1
            for (int kz = 0; kz < 3; ++kz) {
                #pragma unroll 1
                for (int ky = 0; ky < 3; ++ky) {
                    const int vrow = (tz + kz) * (HX * HY) + (ty + ky) * HX + tx;
                    #pragma unroll 1
                    for (int kx = 0; kx < 3; ++kx)
                        body((kz * 3 + ky) * 3 + kx, vrow + kx);
                }
            }
        }
        if (ch + 1 < NCH) __syncthreads();
    }
    // ---- epilogue: bias, relu, occupancy mask ----
    int oz = z0 + tz, oy = y0 + ty, ox = x0 + tx;
    int oflat = (oz * GD + oy) * GD + ox;
    float o = occ[oflat];
    float* op = out + (size_t)oflat * COUT + co_base;
    #pragma unroll
    for (int o4 = 0; o4 < CO_PER / 4; o4++) {
        float4 r;
        r.x = fmaxf(acc4[o4].x + bias[co_base + o4 * 4 + 0], 0.f) * o;
        r.y = fmaxf(acc4[o4].y + bias[co_base + o4 * 4 + 1], 0.f) * o;
        r.z = fmaxf(acc4[o4].z + bias[co_base + o4 * 4 + 2], 0.f) * o;
        r.w = fmaxf(acc4[o4].w + bias[co_base + o4 * 4 + 3], 0.f) * o;
        *reinterpret_cast<float4*>(op + o4 * 4) = r;
    }
}

// ---------------- 2x2x2 stride-2 VALID conv, relu, occupancy mask ----------
template <int CIN, int COUT, int GDI, int CC>
__global__ __launch_bounds__(256) void convd_kernel(
    const float* __restrict__ in, const float* __restrict__ WR,
    const float* __restrict__ bias, const float* __restrict__ occ,
    float* __restrict__ out) {
    constexpr int GDO = GDI / 2;
    constexpr int VOX = 64, NG = 4;
    constexpr int CO_PER = COUT / NG;
    constexpr int HX = 8, HY = 8, HZ = 8, NV = HX * HY * HZ;
    constexpr int Q = CC / 4;
    constexpr int NVp = NV + 8 / Q;
    constexpr int NCH = CIN / CC;
    constexpr int CIN4 = CIN / 4, COUT4 = COUT / 4;
    __shared__ float4 lds4[Q * NVp];

    const int t = threadIdx.x;
    const int x0 = blockIdx.x * 4, y0 = blockIdx.y * 4, z0 = blockIdx.z * 4;
    const int v = t & 63;
    const int g = t >> 6;
    const int tx = v % 4, ty = (v / 4) % 4, tz = v / 16;
    const int co_base = __builtin_amdgcn_readfirstlane(g * CO_PER);
    const int co4b = co_base >> 2;
    const float4* wr4 = reinterpret_cast<const float4*>(WR);

    float4 acc4[CO_PER / 4];
    #pragma unroll
    for (int i = 0; i < CO_PER / 4; i++) acc4[i] = make_float4(0.f, 0.f, 0.f, 0.f);

    for (int ch = 0; ch < NCH; ++ch) {
        constexpr int T4 = NV * Q;
        for (int idx = t; idx < T4; idx += 256) {
            int c4 = idx & (Q - 1);
            int vox = idx / Q;
            int hx = vox % HX, hy = (vox / HX) % HY, hz = vox / (HX * HY);
            int gx = x0 * 2 + hx, gy = y0 * 2 + hy, gz = z0 * 2 + hz;
            lds4[c4 * NVp + vox] = *reinterpret_cast<const float4*>(
                in + (size_t)((gz * GDI + gy) * GDI + gx) * CIN + ch * CC + c4 * 4);
        }
        __syncthreads();
        #pragma unroll 1
        for (int kz = 0; kz < 2; ++kz) {
            #pragma unroll
            for (int ky = 0; ky < 2; ++ky) {
                #pragma unroll
                for (int kx = 0; kx < 2; ++kx) {
                    const int tap = kz * 4 + ky * 2 + kx;
                    const int vin = (tz * 2 + kz) * (HX * HY) + (ty * 2 + ky) * HX + (tx * 2 + kx);
                    #pragma unroll
                    for (int c4 = 0; c4 < Q; ++c4) {
                        float4 iv = lds4[c4 * NVp + vin];
                        const float4* wp =
                            wr4 + ((size_t)(tap * CIN4 + ch * Q + c4) * COUT4) * 4;
                        #pragma unroll
                        for (int o4 = 0; o4 < CO_PER / 4; ++o4) {
                            const float4* w4 = wp + (co4b + o4) * 4;
                            float4 r0 = w4[0], r1 = w4[1], r2 = w4[2], r3 = w4[3];
                            FMA4(iv.x, r0, acc4[o4]);
                            FMA4(iv.y, r1, acc4[o4]);
                            FMA4(iv.z, r2, acc4[o4]);
                            FMA4(iv.w, r3, acc4[o4]);
                        }
                    }
                }
            }
        }
        if (ch + 1 < NCH) __syncthreads();
    }
    int oz = z0 + tz, oy = y0 + ty, ox = x0 + tx;
    int oflat = (oz * GDO + oy) * GDO + ox;
    float o = occ[oflat];
    float* op = out + (size_t)oflat * COUT + co_base;
    #pragma unroll
    for (int o4 = 0; o4 < CO_PER / 4; o4++) {
        float4 r;
        r.x = fmaxf(acc4[o4].x + bias[co_base + o4 * 4 + 0], 0.f) * o;
        r.y = fmaxf(acc4[o4].y + bias[co_base + o4 * 4 + 1], 0.f) * o;
        r.z = fmaxf(acc4[o4].z + bias[co_base + o4 * 4 + 2], 0.f) * o;
        r.w = fmaxf(acc4[o4].w + bias[co_base + o4 * 4 + 3], 0.f) * o;
        *reinterpret_cast<float4*>(op + o4 * 4) = r;
    }
}

// ---------------------------------------------------------------------------
extern "C" void kernel_launch(void* const* d_in, const int* in_sizes, int n_in,
                              void* d_out, int out_size, void* d_ws, size_t ws_size,
                              hipStream_t stream) {
    const int* coords = (const int*)d_in[0];
    const float* feats = (const float*)d_in[1];
    const float* W0 = (const float*)d_in[2];
    const float* b0 = (const float*)d_in[3];
    const float* Wd0 = (const float*)d_in[4];
    const float* bd0 = (const float*)d_in[5];
    const float* W1 = (const float*)d_in[6];
    const float* b1 = (const float*)d_in[7];
    const float* Wd1 = (const float*)d_in[8];
    const float* bd1 = (const float*)d_in[9];
    const float* W2 = (const float*)d_in[10];
    const float* b2 = (const float*)d_in[11];
    const int N = in_sizes[0] / 3;

    // workspace layout (floats)
    float* ws = (float*)d_ws;
    float* x = ws;
    float* h1 = ws;  // reuse x region after conv0 consumes it
    float* occ = ws + 7077888;
    float* h = ws + 7962624;
    float* occ0 = ws + 22118400;
    float* occ1 = ws + 22228992;
    float* WR = ws + 23000000;  // repacked weights, 162176 floats

    float* out = (float*)d_out;
    float* out2 = out;            // 24^3*64
    float* out1 = out + 884736;   // 24^3*64
    float* out0 = out + 1769472;  // 48^3*32

    // repack weights (independent of scatter path)
    repack_all_kernel<<<(WR_TOT + 255) / 256, 256, 0, stream>>>(W0, Wd0, W1, Wd1, W2, WR);

    hipMemsetAsync(x, 0, (size_t)(7077888 + 884736) * sizeof(float), stream);

    scatter_kernel<<<(N + 255) / 256, 256, 0, stream>>>(coords, feats, x, occ, N);
    pool_kernel<48><<<(110592 + 255) / 256, 256, 0, stream>>>(occ, occ0);
    pool_kernel<24><<<(13824 + 255) / 256, 256, 0, stream>>>(occ0, occ1);

    // conv0: 96^3, 8->16, tile 8x8x4, all tap loops unroll-1 (KXU=false)
    conv3_kernel<8, 16, 96, 8, 8, 4, 8, 1, false, false>
        <<<dim3(12, 12, 24), 256, 0, stream>>>(x, WR + WR_W0, b0, occ, h);
    // convd0: 96->48, 16->32
    convd_kernel<16, 32, 96, 16>
        <<<dim3(12, 12, 12), 256, 0, stream>>>(h, WR + WR_WD0, bd0, occ0, out0);
    // conv1: 48^3, 32->32, tile 8x4x4, kx unrolled
    conv3_kernel<32, 32, 48, 8, 4, 4, 32, 1, false, true>
        <<<dim3(6, 12, 12), 256, 0, stream>>>(out0, WR + WR_W1, b1, occ0, h1);
    // convd1: 48->24, 32->64
    convd_kernel<32, 64, 48, 16>
        <<<dim3(6, 6, 6), 256, 0, stream>>>(h1, WR + WR_WD1, bd1, occ1, out1);
    // conv2: 24^3, 64->64, tile 4x4x4 REMAP, COSPLIT=2, kx unrolled
    conv3_kernel<64, 64, 24, 4, 4, 4, 32, 2, true, true>
        <<<dim3(12, 6, 6), 256, 0, stream>>>(out1, WR + WR_W2, b2, occ1, out2);
}

// Round 10
// 486.349 us; speedup vs baseline: 1.6615x; 1.0716x over previous
//
#include <hip/hip_runtime.h>

// ---------------------------------------------------------------------------
// Sparse voxel encoder, fp32 dense pipeline.
// d_out = [out2 (24^3*64) | out1 (24^3*64) | out0 (48^3*32)]
// R8 (resubmitted twice; R8/R9 benches failed at GPU acquisition, never
// measured): conv1 retiled 8x4x4 -> 4x4x4 REMAP (CO_PER 16->8, LDS
// 46.6->27.8KB, 864->1728 blocks) to cut per-wave s_load weight stream and
// raise occupancy; conv2 COSPLIT 2->4 (432->864 blocks) for device fill.
// ---------------------------------------------------------------------------

constexpr int D0 = 96;

// ---------------- scatter: coords/feats -> dense grid + occupancy ----------
__global__ void scatter_kernel(const int* __restrict__ coords,
                               const float* __restrict__ feats,
                               float* __restrict__ x, float* __restrict__ occ,
                               int N) {
    int n = blockIdx.x * blockDim.x + threadIdx.x;
    if (n >= N) return;
    int i = coords[n * 3 + 0], j = coords[n * 3 + 1], k = coords[n * 3 + 2];
    int flat = (i * D0 + j) * D0 + k;
    const float4* f4 = reinterpret_cast<const float4*>(feats + (size_t)n * 8);
    float4 a = f4[0], b = f4[1];
    float* dst = x + (size_t)flat * 8;
    atomicAdd(dst + 0, a.x); atomicAdd(dst + 1, a.y);
    atomicAdd(dst + 2, a.z); atomicAdd(dst + 3, a.w);
    atomicAdd(dst + 4, b.x); atomicAdd(dst + 5, b.y);
    atomicAdd(dst + 6, b.z); atomicAdd(dst + 7, b.w);
    occ[flat] = 1.0f;
}

// ---------------- 2x2x2 max pool on occupancy ------------------------------
template <int GDO>
__global__ void pool_kernel(const float* __restrict__ occ_in,
                            float* __restrict__ occ_out) {
    int idx = blockIdx.x * blockDim.x + threadIdx.x;
    if (idx >= GDO * GDO * GDO) return;
    int x = idx % GDO, y = (idx / GDO) % GDO, z = idx / (GDO * GDO);
    constexpr int GDI = GDO * 2;
    float m = 0.f;
    #pragma unroll
    for (int dz = 0; dz < 2; dz++)
        #pragma unroll
        for (int dy = 0; dy < 2; dy++)
            #pragma unroll
            for (int dx = 0; dx < 2; dx++)
                m = fmaxf(m, occ_in[((z * 2 + dz) * GDI + y * 2 + dy) * GDI + x * 2 + dx]);
    occ_out[idx] = m;
}

// ---------------- weight repack -------------------------------------------
// dst[i]: i = (((tap*CIN4 + c4)*COUT4 + o4)*4 + r)*4 + c
//   == W[(tap*CIN + c4*4+r)*COUT + o4*4+c]
__device__ inline void repack_one(const float* __restrict__ W,
                                  float* __restrict__ WR, int i, int CIN, int COUT) {
    int c = i & 3;
    int r = (i >> 2) & 3;
    int blk = i >> 4;
    int COUT4 = COUT >> 2, CIN4 = CIN >> 2;
    int o4 = blk % COUT4;
    int c4 = (blk / COUT4) % CIN4;
    int tap = blk / (COUT4 * CIN4);
    WR[i] = W[((size_t)tap * CIN + c4 * 4 + r) * COUT + o4 * 4 + c];
}

constexpr int WR_W0 = 0;              // 27*8*16    = 3456
constexpr int WR_WD0 = 3456;          // 8*16*32    = 4096
constexpr int WR_W1 = 7552;           // 27*32*32   = 27648
constexpr int WR_WD1 = 35200;         // 8*32*64    = 16384
constexpr int WR_W2 = 51584;          // 27*64*64   = 110592
constexpr int WR_TOT = 162176;

__global__ void repack_all_kernel(const float* __restrict__ W0,
                                  const float* __restrict__ Wd0,
                                  const float* __restrict__ W1,
                                  const float* __restrict__ Wd1,
                                  const float* __restrict__ W2,
                                  float* __restrict__ WR) {
    int i = blockIdx.x * 256 + threadIdx.x;
    if (i < WR_WD0)          repack_one(W0,  WR + WR_W0,  i - WR_W0,  8, 16);
    else if (i < WR_W1)      repack_one(Wd0, WR + WR_WD0, i - WR_WD0, 16, 32);
    else if (i < WR_WD1)     repack_one(W1,  WR + WR_W1,  i - WR_W1,  32, 32);
    else if (i < WR_W2)      repack_one(Wd1, WR + WR_WD1, i - WR_WD1, 32, 64);
    else if (i < WR_TOT)     repack_one(W2,  WR + WR_W2,  i - WR_W2,  64, 64);
}

#define FMA4(av, rv, accv)                 \
    accv.x = fmaf(av, rv.x, accv.x);       \
    accv.y = fmaf(av, rv.y, accv.y);       \
    accv.z = fmaf(av, rv.z, accv.z);       \
    accv.w = fmaf(av, rv.w, accv.w);

// ---------------- 3x3x3 SAME conv, relu, occupancy mask --------------------
template <int CIN, int COUT, int GD, int TX, int TY, int TZ, int CC, int COSPLIT,
          bool REMAP, bool KXU>
__global__ __launch_bounds__(256) void conv3_kernel(
    const float* __restrict__ in, const float* __restrict__ WR,
    const float* __restrict__ bias, const float* __restrict__ occ,
    float* __restrict__ out) {
    constexpr int HX = TX + 2, HY = TY + 2, HZ = TZ + 2;
    constexpr int NV = HX * HY * HZ;
    constexpr int Q = CC / 4;
    constexpr int PADV = 8 / Q;
    constexpr int NVp = NV + PADV;
    constexpr int VOX = TX * TY * TZ;
    constexpr int NG = 256 / VOX;
    constexpr int CO_PER = COUT / COSPLIT / NG;
    constexpr int NCH = CIN / CC;
    constexpr int CIN4 = CIN / 4, COUT4 = COUT / 4;
    __shared__ float4 lds4[Q * NVp];

    const int t = threadIdx.x;
    constexpr int NBX = GD / TX;
    const int cs = blockIdx.x / NBX;
    const int bx = blockIdx.x % NBX;
    const int x0 = bx * TX, y0 = blockIdx.y * TY, z0 = blockIdx.z * TZ;
    const int v = t & (VOX - 1);
    const int g = t / VOX;  // wave-uniform (VOX >= 64)
    int tx, ty, tz;
    if (REMAP) {  // VOX==64, 4x4x4
        tx = v & 3;
        ty = (v >> 3) & 3;
        tz = ((v >> 2) & 1) | (((v >> 5) & 1) << 1);
    } else {
        tx = v % TX;
        ty = (v / TX) % TY;
        tz = v / (TX * TY);
    }
    const int co_base = __builtin_amdgcn_readfirstlane((cs * NG + g) * CO_PER);
    const int co4b = co_base >> 2;
    const float4* wr4 = reinterpret_cast<const float4*>(WR);

    float4 acc4[CO_PER / 4];
    #pragma unroll
    for (int i = 0; i < CO_PER / 4; i++) acc4[i] = make_float4(0.f, 0.f, 0.f, 0.f);

    for (int ch = 0; ch < NCH; ++ch) {
        // ---- stage halo tile ----
        constexpr int T4 = NV * Q;
        for (int idx = t; idx < T4; idx += 256) {
            int c4 = idx & (Q - 1);
            int vox = idx / Q;
            int hx = vox % HX, hy = (vox / HX) % HY, hz = vox / (HX * HY);
            int gx = x0 + hx - 1, gy = y0 + hy - 1, gz = z0 + hz - 1;
            float4 val = make_float4(0.f, 0.f, 0.f, 0.f);
            if (gx >= 0 && gx < GD && gy >= 0 && gy < GD && gz >= 0 && gz < GD) {
                val = *reinterpret_cast<const float4*>(
                    in + (size_t)((gz * GD + gy) * GD + gx) * CIN + ch * CC + c4 * 4);
            }
            lds4[c4 * NVp + vox] = val;
        }
        __syncthreads();

        auto body = [&](int tap, int vin) {
            #pragma unroll
            for (int c4 = 0; c4 < Q; ++c4) {
                float4 iv = lds4[c4 * NVp + vin];
                const float4* wp =
                    wr4 + ((size_t)(tap * CIN4 + ch * Q + c4) * COUT4) * 4;
                #pragma unroll
                for (int o4 = 0; o4 < CO_PER / 4; ++o4) {
                    const float4* w4 = wp + (co4b + o4) * 4;
                    float4 r0 = w4[0], r1 = w4[1], r2 = w4[2], r3 = w4[3];
                    FMA4(iv.x, r0, acc4[o4]);
                    FMA4(iv.y, r1, acc4[o4]);
                    FMA4(iv.z, r2, acc4[o4]);
                    FMA4(iv.w, r3, acc4[o4]);
                }
            }
        };

        if constexpr (KXU) {
            #pragma unroll 1
            for (int kz = 0; kz < 3; ++kz) {
                #pragma unroll 1
                for (int ky = 0; ky < 3; ++ky) {
                    const int vrow = (tz + kz) * (HX * HY) + (ty + ky) * HX + tx;
                    #pragma unroll
                    for (int kx = 0; kx < 3; ++kx)
                        body((kz * 3 + ky) * 3 + kx, vrow + kx);
                }
            }
        } else {
            #pragma unroll 1
            for (int kz = 0; kz < 3; ++kz) {
                #pragma unroll 1
                for (int ky = 0; ky < 3; ++ky) {
                    const int vrow = (tz + kz) * (HX * HY) + (ty + ky) * HX + tx;
                    #pragma unroll 1
                    for (int kx = 0; kx < 3; ++kx)
                        body((kz * 3 + ky) * 3 + kx, vrow + kx);
                }
            }
        }
        if (ch + 1 < NCH) __syncthreads();
    }
    // ---- epilogue: bias, relu, occupancy mask ----
    int oz = z0 + tz, oy = y0 + ty, ox = x0 + tx;
    int oflat = (oz * GD + oy) * GD + ox;
    float o = occ[oflat];
    float* op = out + (size_t)oflat * COUT + co_base;
    #pragma unroll
    for (int o4 = 0; o4 < CO_PER / 4; o4++) {
        float4 r;
        r.x = fmaxf(acc4[o4].x + bias[co_base + o4 * 4 + 0], 0.f) * o;
        r.y = fmaxf(acc4[o4].y + bias[co_base + o4 * 4 + 1], 0.f) * o;
        r.z = fmaxf(acc4[o4].z + bias[co_base + o4 * 4 + 2], 0.f) * o;
        r.w = fmaxf(acc4[o4].w + bias[co_base + o4 * 4 + 3], 0.f) * o;
        *reinterpret_cast<float4*>(op + o4 * 4) = r;
    }
}

// ---------------- 2x2x2 stride-2 VALID conv, relu, occupancy mask ----------
template <int CIN, int COUT, int GDI, int CC>
__global__ __launch_bounds__(256) void convd_kernel(
    const float* __restrict__ in, const float* __restrict__ WR,
    const float* __restrict__ bias, const float* __restrict__ occ,
    float* __restrict__ out) {
    constexpr int GDO = GDI / 2;
    constexpr int VOX = 64, NG = 4;
    constexpr int CO_PER = COUT / NG;
    constexpr int HX = 8, HY = 8, HZ = 8, NV = HX * HY * HZ;
    constexpr int Q = CC / 4;
    constexpr int NVp = NV + 8 / Q;
    constexpr int NCH = CIN / CC;
    constexpr int CIN4 = CIN / 4, COUT4 = COUT / 4;
    __shared__ float4 lds4[Q * NVp];

    const int t = threadIdx.x;
    const int x0 = blockIdx.x * 4, y0 = blockIdx.y * 4, z0 = blockIdx.z * 4;
    const int v = t & 63;
    const int g = t >> 6;
    const int tx = v % 4, ty = (v / 4) % 4, tz = v / 16;
    const int co_base = __builtin_amdgcn_readfirstlane(g * CO_PER);
    const int co4b = co_base >> 2;
    const float4* wr4 = reinterpret_cast<const float4*>(WR);

    float4 acc4[CO_PER / 4];
    #pragma unroll
    for (int i = 0; i < CO_PER / 4; i++) acc4[i] = make_float4(0.f, 0.f, 0.f, 0.f);

    for (int ch = 0; ch < NCH; ++ch) {
        constexpr int T4 = NV * Q;
        for (int idx = t; idx < T4; idx += 256) {
            int c4 = idx & (Q - 1);
            int vox = idx / Q;
            int hx = vox % HX, hy = (vox / HX) % HY, hz = vox / (HX * HY);
            int gx = x0 * 2 + hx, gy = y0 * 2 + hy, gz = z0 * 2 + hz;
            lds4[c4 * NVp + vox] = *reinterpret_cast<const float4*>(
                in + (size_t)((gz * GDI + gy) * GDI + gx) * CIN + ch * CC + c4 * 4);
        }
        __syncthreads();
        #pragma unroll 1
        for (int kz = 0; kz < 2; ++kz) {
            #pragma unroll
            for (int ky = 0; ky < 2; ++ky) {
                #pragma unroll
                for (int kx = 0; kx < 2; ++kx) {
                    const int tap = kz * 4 + ky * 2 + kx;
                    const int vin = (tz * 2 + kz) * (HX * HY) + (ty * 2 + ky) * HX + (tx * 2 + kx);
                    #pragma unroll
                    for (int c4 = 0; c4 < Q; ++c4) {
                        float4 iv = lds4[c4 * NVp + vin];
                        const float4* wp =
                            wr4 + ((size_t)(tap * CIN4 + ch * Q + c4) * COUT4) * 4;
                        #pragma unroll
                        for (int o4 = 0; o4 < CO_PER / 4; ++o4) {
                            const float4* w4 = wp + (co4b + o4) * 4;
                            float4 r0 = w4[0], r1 = w4[1], r2 = w4[2], r3 = w4[3];
                            FMA4(iv.x, r0, acc4[o4]);
                            FMA4(iv.y, r1, acc4[o4]);
                            FMA4(iv.z, r2, acc4[o4]);
                            FMA4(iv.w, r3, acc4[o4]);
                        }
                    }
                }
            }
        }
        if (ch + 1 < NCH) __syncthreads();
    }
    int oz = z0 + tz, oy = y0 + ty, ox = x0 + tx;
    int oflat = (oz * GDO + oy) * GDO + ox;
    float o = occ[oflat];
    float* op = out + (size_t)oflat * COUT + co_base;
    #pragma unroll
    for (int o4 = 0; o4 < CO_PER / 4; o4++) {
        float4 r;
        r.x = fmaxf(acc4[o4].x + bias[co_base + o4 * 4 + 0], 0.f) * o;
        r.y = fmaxf(acc4[o4].y + bias[co_base + o4 * 4 + 1], 0.f) * o;
        r.z = fmaxf(acc4[o4].z + bias[co_base + o4 * 4 + 2], 0.f) * o;
        r.w = fmaxf(acc4[o4].w + bias[co_base + o4 * 4 + 3], 0.f) * o;
        *reinterpret_cast<float4*>(op + o4 * 4) = r;
    }
}

// ---------------------------------------------------------------------------
extern "C" void kernel_launch(void* const* d_in, const int* in_sizes, int n_in,
                              void* d_out, int out_size, void* d_ws, size_t ws_size,
                              hipStream_t stream) {
    const int* coords = (const int*)d_in[0];
    const float* feats = (const float*)d_in[1];
    const float* W0 = (const float*)d_in[2];
    const float* b0 = (const float*)d_in[3];
    const float* Wd0 = (const float*)d_in[4];
    const float* bd0 = (const float*)d_in[5];
    const float* W1 = (const float*)d_in[6];
    const float* b1 = (const float*)d_in[7];
    const float* Wd1 = (const float*)d_in[8];
    const float* bd1 = (const float*)d_in[9];
    const float* W2 = (const float*)d_in[10];
    const float* b2 = (const float*)d_in[11];
    const int N = in_sizes[0] / 3;

    // workspace layout (floats)
    float* ws = (float*)d_ws;
    float* x = ws;
    float* h1 = ws;  // reuse x region after conv0 consumes it
    float* occ = ws + 7077888;
    float* h = ws + 7962624;
    float* occ0 = ws + 22118400;
    float* occ1 = ws + 22228992;
    float* WR = ws + 23000000;  // repacked weights, 162176 floats

    float* out = (float*)d_out;
    float* out2 = out;            // 24^3*64
    float* out1 = out + 884736;   // 24^3*64
    float* out0 = out + 1769472;  // 48^3*32

    repack_all_kernel<<<(WR_TOT + 255) / 256, 256, 0, stream>>>(W0, Wd0, W1, Wd1, W2, WR);

    hipMemsetAsync(x, 0, (size_t)(7077888 + 884736) * sizeof(float), stream);

    scatter_kernel<<<(N + 255) / 256, 256, 0, stream>>>(coords, feats, x, occ, N);
    pool_kernel<48><<<(110592 + 255) / 256, 256, 0, stream>>>(occ, occ0);
    pool_kernel<24><<<(13824 + 255) / 256, 256, 0, stream>>>(occ0, occ1);

    // conv0: 96^3, 8->16, tile 8x8x4, all tap loops unroll-1 (KXU=false)
    conv3_kernel<8, 16, 96, 8, 8, 4, 8, 1, false, false>
        <<<dim3(12, 12, 24), 256, 0, stream>>>(x, WR + WR_W0, b0, occ, h);
    // convd0: 96->48, 16->32
    convd_kernel<16, 32, 96, 16>
        <<<dim3(12, 12, 12), 256, 0, stream>>>(h, WR + WR_WD0, bd0, occ0, out0);
    // conv1: 48^3, 32->32, tile 4x4x4 REMAP, CO_PER=8, 1728 blocks, 27.8KB LDS
    conv3_kernel<32, 32, 48, 4, 4, 4, 32, 1, true, true>
        <<<dim3(12, 12, 12), 256, 0, stream>>>(out0, WR + WR_W1, b1, occ0, h1);
    // convd1: 48->24, 32->64
    convd_kernel<32, 64, 48, 16>
        <<<dim3(6, 6, 6), 256, 0, stream>>>(h1, WR + WR_WD1, bd1, occ1, out1);
    // conv2: 24^3, 64->64, tile 4x4x4 REMAP, COSPLIT=4 (CO_PER=4, 864 blocks)
    conv3_kernel<64, 64, 24, 4, 4, 4, 32, 4, true, true>
        <<<dim3(24, 6, 6), 256, 0, stream>>>(out1, WR + WR_W2, b2, occ1, out2);
}

// Round 11
// 445.060 us; speedup vs baseline: 1.8156x; 1.0928x over previous
//
#include <hip/hip_runtime.h>

// ---------------------------------------------------------------------------
// Sparse voxel encoder, fp32 dense pipeline.
// d_out = [out2 (24^3*64) | out1 (24^3*64) | out0 (48^3*32)]
// R10: conv0 retiled 8x8x4 -> 4x4x4 REMAP (CO_PER 16->4, LDS 19.4->6.9KB,
// 3456->13824 blocks, KXU on). R8's conv1 retile measured +: 521->486us,
// conv1 left top-5; conv0 was top at 118us / VGPR=20 (no ILP headroom).
// ---------------------------------------------------------------------------

constexpr int D0 = 96;

// ---------------- scatter: coords/feats -> dense grid + occupancy ----------
__global__ void scatter_kernel(const int* __restrict__ coords,
                               const float* __restrict__ feats,
                               float* __restrict__ x, float* __restrict__ occ,
                               int N) {
    int n = blockIdx.x * blockDim.x + threadIdx.x;
    if (n >= N) return;
    int i = coords[n * 3 + 0], j = coords[n * 3 + 1], k = coords[n * 3 + 2];
    int flat = (i * D0 + j) * D0 + k;
    const float4* f4 = reinterpret_cast<const float4*>(feats + (size_t)n * 8);
    float4 a = f4[0], b = f4[1];
    float* dst = x + (size_t)flat * 8;
    atomicAdd(dst + 0, a.x); atomicAdd(dst + 1, a.y);
    atomicAdd(dst + 2, a.z); atomicAdd(dst + 3, a.w);
    atomicAdd(dst + 4, b.x); atomicAdd(dst + 5, b.y);
    atomicAdd(dst + 6, b.z); atomicAdd(dst + 7, b.w);
    occ[flat] = 1.0f;
}

// ---------------- 2x2x2 max pool on occupancy ------------------------------
template <int GDO>
__global__ void pool_kernel(const float* __restrict__ occ_in,
                            float* __restrict__ occ_out) {
    int idx = blockIdx.x * blockDim.x + threadIdx.x;
    if (idx >= GDO * GDO * GDO) return;
    int x = idx % GDO, y = (idx / GDO) % GDO, z = idx / (GDO * GDO);
    constexpr int GDI = GDO * 2;
    float m = 0.f;
    #pragma unroll
    for (int dz = 0; dz < 2; dz++)
        #pragma unroll
        for (int dy = 0; dy < 2; dy++)
            #pragma unroll
            for (int dx = 0; dx < 2; dx++)
                m = fmaxf(m, occ_in[((z * 2 + dz) * GDI + y * 2 + dy) * GDI + x * 2 + dx]);
    occ_out[idx] = m;
}

// ---------------- weight repack -------------------------------------------
// dst[i]: i = (((tap*CIN4 + c4)*COUT4 + o4)*4 + r)*4 + c
//   == W[(tap*CIN + c4*4+r)*COUT + o4*4+c]
__device__ inline void repack_one(const float* __restrict__ W,
                                  float* __restrict__ WR, int i, int CIN, int COUT) {
    int c = i & 3;
    int r = (i >> 2) & 3;
    int blk = i >> 4;
    int COUT4 = COUT >> 2, CIN4 = CIN >> 2;
    int o4 = blk % COUT4;
    int c4 = (blk / COUT4) % CIN4;
    int tap = blk / (COUT4 * CIN4);
    WR[i] = W[((size_t)tap * CIN + c4 * 4 + r) * COUT + o4 * 4 + c];
}

constexpr int WR_W0 = 0;              // 27*8*16    = 3456
constexpr int WR_WD0 = 3456;          // 8*16*32    = 4096
constexpr int WR_W1 = 7552;           // 27*32*32   = 27648
constexpr int WR_WD1 = 35200;         // 8*32*64    = 16384
constexpr int WR_W2 = 51584;          // 27*64*64   = 110592
constexpr int WR_TOT = 162176;

__global__ void repack_all_kernel(const float* __restrict__ W0,
                                  const float* __restrict__ Wd0,
                                  const float* __restrict__ W1,
                                  const float* __restrict__ Wd1,
                                  const float* __restrict__ W2,
                                  float* __restrict__ WR) {
    int i = blockIdx.x * 256 + threadIdx.x;
    if (i < WR_WD0)          repack_one(W0,  WR + WR_W0,  i - WR_W0,  8, 16);
    else if (i < WR_W1)      repack_one(Wd0, WR + WR_WD0, i - WR_WD0, 16, 32);
    else if (i < WR_WD1)     repack_one(W1,  WR + WR_W1,  i - WR_W1,  32, 32);
    else if (i < WR_W2)      repack_one(Wd1, WR + WR_WD1, i - WR_WD1, 32, 64);
    else if (i < WR_TOT)     repack_one(W2,  WR + WR_W2,  i - WR_W2,  64, 64);
}

#define FMA4(av, rv, accv)                 \
    accv.x = fmaf(av, rv.x, accv.x);       \
    accv.y = fmaf(av, rv.y, accv.y);       \
    accv.z = fmaf(av, rv.z, accv.z);       \
    accv.w = fmaf(av, rv.w, accv.w);

// ---------------- 3x3x3 SAME conv, relu, occupancy mask --------------------
template <int CIN, int COUT, int GD, int TX, int TY, int TZ, int CC, int COSPLIT,
          bool REMAP, bool KXU>
__global__ __launch_bounds__(256) void conv3_kernel(
    const float* __restrict__ in, const float* __restrict__ WR,
    const float* __restrict__ bias, const float* __restrict__ occ,
    float* __restrict__ out) {
    constexpr int HX = TX + 2, HY = TY + 2, HZ = TZ + 2;
    constexpr int NV = HX * HY * HZ;
    constexpr int Q = CC / 4;
    constexpr int PADV = 8 / Q;
    constexpr int NVp = NV + PADV;
    constexpr int VOX = TX * TY * TZ;
    constexpr int NG = 256 / VOX;
    constexpr int CO_PER = COUT / COSPLIT / NG;
    constexpr int NCH = CIN / CC;
    constexpr int CIN4 = CIN / 4, COUT4 = COUT / 4;
    __shared__ float4 lds4[Q * NVp];

    const int t = threadIdx.x;
    constexpr int NBX = GD / TX;
    const int cs = blockIdx.x / NBX;
    const int bx = blockIdx.x % NBX;
    const int x0 = bx * TX, y0 = blockIdx.y * TY, z0 = blockIdx.z * TZ;
    const int v = t & (VOX - 1);
    const int g = t / VOX;  // wave-uniform (VOX >= 64)
    int tx, ty, tz;
    if (REMAP) {  // VOX==64, 4x4x4
        tx = v & 3;
        ty = (v >> 3) & 3;
        tz = ((v >> 2) & 1) | (((v >> 5) & 1) << 1);
    } else {
        tx = v % TX;
        ty = (v / TX) % TY;
        tz = v / (TX * TY);
    }
    const int co_base = __builtin_amdgcn_readfirstlane((cs * NG + g) * CO_PER);
    const int co4b = co_base >> 2;
    const float4* wr4 = reinterpret_cast<const float4*>(WR);

    float4 acc4[CO_PER / 4];
    #pragma unroll
    for (int i = 0; i < CO_PER / 4; i++) acc4[i] = make_float4(0.f, 0.f, 0.f, 0.f);

    for (int ch = 0; ch < NCH; ++ch) {
        // ---- stage halo tile ----
        constexpr int T4 = NV * Q;
        for (int idx = t; idx < T4; idx += 256) {
            int c4 = idx & (Q - 1);
            int vox = idx / Q;
            int hx = vox % HX, hy = (vox / HX) % HY, hz = vox / (HX * HY);
            int gx = x0 + hx - 1, gy = y0 + hy - 1, gz = z0 + hz - 1;
            float4 val = make_float4(0.f, 0.f, 0.f, 0.f);
            if (gx >= 0 && gx < GD && gy >= 0 && gy < GD && gz >= 0 && gz < GD) {
                val = *reinterpret_cast<const float4*>(
                    in + (size_t)((gz * GD + gy) * GD + gx) * CIN + ch * CC + c4 * 4);
            }
            lds4[c4 * NVp + vox] = val;
        }
        __syncthreads();

        auto body = [&](int tap, int vin) {
            #pragma unroll
            for (int c4 = 0; c4 < Q; ++c4) {
                float4 iv = lds4[c4 * NVp + vin];
                const float4* wp =
                    wr4 + ((size_t)(tap * CIN4 + ch * Q + c4) * COUT4) * 4;
                #pragma unroll
                for (int o4 = 0; o4 < CO_PER / 4; ++o4) {
                    const float4* w4 = wp + (co4b + o4) * 4;
                    float4 r0 = w4[0], r1 = w4[1], r2 = w4[2], r3 = w4[3];
                    FMA4(iv.x, r0, acc4[o4]);
                    FMA4(iv.y, r1, acc4[o4]);
                    FMA4(iv.z, r2, acc4[o4]);
                    FMA4(iv.w, r3, acc4[o4]);
                }
            }
        };

        if constexpr (KXU) {
            #pragma unroll 1
            for (int kz = 0; kz < 3; ++kz) {
                #pragma unroll 1
                for (int ky = 0; ky < 3; ++ky) {
                    const int vrow = (tz + kz) * (HX * HY) + (ty + ky) * HX + tx;
                    #pragma unroll
                    for (int kx = 0; kx < 3; ++kx)
                        body((kz * 3 + ky) * 3 + kx, vrow + kx);
                }
            }
        } else {
            #pragma unroll 1
            for (int kz = 0; kz < 3; ++kz) {
                #pragma unroll 1
                for (int ky = 0; ky < 3; ++ky) {
                    const int vrow = (tz + kz) * (HX * HY) + (ty + ky) * HX + tx;
                    #pragma unroll 1
                    for (int kx = 0; kx < 3; ++kx)
                        body((kz * 3 + ky) * 3 + kx, vrow + kx);
                }
            }
        }
        if (ch + 1 < NCH) __syncthreads();
    }
    // ---- epilogue: bias, relu, occupancy mask ----
    int oz = z0 + tz, oy = y0 + ty, ox = x0 + tx;
    int oflat = (oz * GD + oy) * GD + ox;
    float o = occ[oflat];
    float* op = out + (size_t)oflat * COUT + co_base;
    #pragma unroll
    for (int o4 = 0; o4 < CO_PER / 4; o4++) {
        float4 r;
        r.x = fmaxf(acc4[o4].x + bias[co_base + o4 * 4 + 0], 0.f) * o;
        r.y = fmaxf(acc4[o4].y + bias[co_base + o4 * 4 + 1], 0.f) * o;
        r.z = fmaxf(acc4[o4].z + bias[co_base + o4 * 4 + 2], 0.f) * o;
        r.w = fmaxf(acc4[o4].w + bias[co_base + o4 * 4 + 3], 0.f) * o;
        *reinterpret_cast<float4*>(op + o4 * 4) = r;
    }
}

// ---------------- 2x2x2 stride-2 VALID conv, relu, occupancy mask ----------
template <int CIN, int COUT, int GDI, int CC>
__global__ __launch_bounds__(256) void convd_kernel(
    const float* __restrict__ in, const float* __restrict__ WR,
    const float* __restrict__ bias, const float* __restrict__ occ,
    float* __restrict__ out) {
    constexpr int GDO = GDI / 2;
    constexpr int VOX = 64, NG = 4;
    constexpr int CO_PER = COUT / NG;
    constexpr int HX = 8, HY = 8, HZ = 8, NV = HX * HY * HZ;
    constexpr int Q = CC / 4;
    constexpr int NVp = NV + 8 / Q;
    constexpr int NCH = CIN / CC;
    constexpr int CIN4 = CIN / 4, COUT4 = COUT / 4;
    __shared__ float4 lds4[Q * NVp];

    const int t = threadIdx.x;
    const int x0 = blockIdx.x * 4, y0 = blockIdx.y * 4, z0 = blockIdx.z * 4;
    const int v = t & 63;
    const int g = t >> 6;
    const int tx = v % 4, ty = (v / 4) % 4, tz = v / 16;
    const int co_base = __builtin_amdgcn_readfirstlane(g * CO_PER);
    const int co4b = co_base >> 2;
    const float4* wr4 = reinterpret_cast<const float4*>(WR);

    float4 acc4[CO_PER / 4];
    #pragma unroll
    for (int i = 0; i < CO_PER / 4; i++) acc4[i] = make_float4(0.f, 0.f, 0.f, 0.f);

    for (int ch = 0; ch < NCH; ++ch) {
        constexpr int T4 = NV * Q;
        for (int idx = t; idx < T4; idx += 256) {
            int c4 = idx & (Q - 1);
            int vox = idx / Q;
            int hx = vox % HX, hy = (vox / HX) % HY, hz = vox / (HX * HY);
            int gx = x0 * 2 + hx, gy = y0 * 2 + hy, gz = z0 * 2 + hz;
            lds4[c4 * NVp + vox] = *reinterpret_cast<const float4*>(
                in + (size_t)((gz * GDI + gy) * GDI + gx) * CIN + ch * CC + c4 * 4);
        }
        __syncthreads();
        #pragma unroll 1
        for (int kz = 0; kz < 2; ++kz) {
            #pragma unroll
            for (int ky = 0; ky < 2; ++ky) {
                #pragma unroll
                for (int kx = 0; kx < 2; ++kx) {
                    const int tap = kz * 4 + ky * 2 + kx;
                    const int vin = (tz * 2 + kz) * (HX * HY) + (ty * 2 + ky) * HX + (tx * 2 + kx);
                    #pragma unroll
                    for (int c4 = 0; c4 < Q; ++c4) {
                        float4 iv = lds4[c4 * NVp + vin];
                        const float4* wp =
                            wr4 + ((size_t)(tap * CIN4 + ch * Q + c4) * COUT4) * 4;
                        #pragma unroll
                        for (int o4 = 0; o4 < CO_PER / 4; ++o4) {
                            const float4* w4 = wp + (co4b + o4) * 4;
                            float4 r0 = w4[0], r1 = w4[1], r2 = w4[2], r3 = w4[3];
                            FMA4(iv.x, r0, acc4[o4]);
                            FMA4(iv.y, r1, acc4[o4]);
                            FMA4(iv.z, r2, acc4[o4]);
                            FMA4(iv.w, r3, acc4[o4]);
                        }
                    }
                }
            }
        }
        if (ch + 1 < NCH) __syncthreads();
    }
    int oz = z0 + tz, oy = y0 + ty, ox = x0 + tx;
    int oflat = (oz * GDO + oy) * GDO + ox;
    float o = occ[oflat];
    float* op = out + (size_t)oflat * COUT + co_base;
    #pragma unroll
    for (int o4 = 0; o4 < CO_PER / 4; o4++) {
        float4 r;
        r.x = fmaxf(acc4[o4].x + bias[co_base + o4 * 4 + 0], 0.f) * o;
        r.y = fmaxf(acc4[o4].y + bias[co_base + o4 * 4 + 1], 0.f) * o;
        r.z = fmaxf(acc4[o4].z + bias[co_base + o4 * 4 + 2], 0.f) * o;
        r.w = fmaxf(acc4[o4].w + bias[co_base + o4 * 4 + 3], 0.f) * o;
        *reinterpret_cast<float4*>(op + o4 * 4) = r;
    }
}

// ---------------------------------------------------------------------------
extern "C" void kernel_launch(void* const* d_in, const int* in_sizes, int n_in,
                              void* d_out, int out_size, void* d_ws, size_t ws_size,
                              hipStream_t stream) {
    const int* coords = (const int*)d_in[0];
    const float* feats = (const float*)d_in[1];
    const float* W0 = (const float*)d_in[2];
    const float* b0 = (const float*)d_in[3];
    const float* Wd0 = (const float*)d_in[4];
    const float* bd0 = (const float*)d_in[5];
    const float* W1 = (const float*)d_in[6];
    const float* b1 = (const float*)d_in[7];
    const float* Wd1 = (const float*)d_in[8];
    const float* bd1 = (const float*)d_in[9];
    const float* W2 = (const float*)d_in[10];
    const float* b2 = (const float*)d_in[11];
    const int N = in_sizes[0] / 3;

    // workspace layout (floats)
    float* ws = (float*)d_ws;
    float* x = ws;
    float* h1 = ws;  // reuse x region after conv0 consumes it
    float* occ = ws + 7077888;
    float* h = ws + 7962624;
    float* occ0 = ws + 22118400;
    float* occ1 = ws + 22228992;
    float* WR = ws + 23000000;  // repacked weights, 162176 floats

    float* out = (float*)d_out;
    float* out2 = out;            // 24^3*64
    float* out1 = out + 884736;   // 24^3*64
    float* out0 = out + 1769472;  // 48^3*32

    repack_all_kernel<<<(WR_TOT + 255) / 256, 256, 0, stream>>>(W0, Wd0, W1, Wd1, W2, WR);

    hipMemsetAsync(x, 0, (size_t)(7077888 + 884736) * sizeof(float), stream);

    scatter_kernel<<<(N + 255) / 256, 256, 0, stream>>>(coords, feats, x, occ, N);
    pool_kernel<48><<<(110592 + 255) / 256, 256, 0, stream>>>(occ, occ0);
    pool_kernel<24><<<(13824 + 255) / 256, 256, 0, stream>>>(occ0, occ1);

    // conv0: 96^3, 8->16, tile 4x4x4 REMAP, CO_PER=4, 13824 blocks, 6.9KB LDS
    conv3_kernel<8, 16, 96, 4, 4, 4, 8, 1, true, true>
        <<<dim3(24, 24, 24), 256, 0, stream>>>(x, WR + WR_W0, b0, occ, h);
    // convd0: 96->48, 16->32
    convd_kernel<16, 32, 96, 16>
        <<<dim3(12, 12, 12), 256, 0, stream>>>(h, WR + WR_WD0, bd0, occ0, out0);
    // conv1: 48^3, 32->32, tile 4x4x4 REMAP, CO_PER=8, 1728 blocks, 27.8KB LDS
    conv3_kernel<32, 32, 48, 4, 4, 4, 32, 1, true, true>
        <<<dim3(12, 12, 12), 256, 0, stream>>>(out0, WR + WR_W1, b1, occ0, h1);
    // convd1: 48->24, 32->64
    convd_kernel<32, 64, 48, 16>
        <<<dim3(6, 6, 6), 256, 0, stream>>>(h1, WR + WR_WD1, bd1, occ1, out1);
    // conv2: 24^3, 64->64, tile 4x4x4 REMAP, COSPLIT=4 (CO_PER=4, 864 blocks)
    conv3_kernel<64, 64, 24, 4, 4, 4, 32, 4, true, true>
        <<<dim3(24, 6, 6), 256, 0, stream>>>(out1, WR + WR_W2, b2, occ1, out2);
}